// Round 17
// baseline (2268.000 us; speedup 1.0000x reference)
//
#include <hip/hip_runtime.h>
#include <cstddef>

#define HH 128
#define WW2 128
#define HWSZ (HH*WW2)
#define CCH 256

typedef __attribute__((ext_vector_type(8))) short short8v;   // 8 bf16 = 4 VGPR
typedef __attribute__((ext_vector_type(16))) float f32x16;   // MFMA 32x32 acc
typedef __attribute__((ext_vector_type(4)))  float f32x4;    // MFMA 16x16 acc

__device__ __forceinline__ ushort bf16rte(float v) {
    uint u = __float_as_uint(v);
    uint r = u + 0x7FFFu + ((u >> 16) & 1u);
    return (ushort)(r >> 16);
}

// ---------------- conv weight: fold (l1s*l1w + center l2s*l2w) AND split into
// 32x32 A-fragment order hi/lo bf16, in one pass (no Wf round-trip)
__global__ __launch_bounds__(256) void k_wsplit(const float* __restrict__ l1w, const float* __restrict__ l1s,
                                                const float* __restrict__ l2w, const float* __restrict__ l2s,
                                                ushort* __restrict__ ahi, ushort* __restrict__ alo) {
    int idx = blockIdx.x * 256 + threadIdx.x;     // 589824 total
    if (idx >= 589824) return;
    int j    = idx & 7;
    int lane = (idx >> 3) & 63;
    int t2   = idx >> 9;
    int kb   = t2 % 144;
    int cob  = t2 / 144;
    int cc  = kb / 18; int rem = kb - cc * 18; int tap = rem >> 1; int ks = rem & 1;
    int ci  = cc * 32 + ks * 16 + ((lane >> 5) << 3) + j;
    int co  = cob * 32 + (lane & 31);
    float v = l1s[co] * l1w[(size_t)co * 2304 + ci * 9 + tap];
    if (tap == 4) v += l2s[co] * l2w[(size_t)co * 256 + ci];
    ushort h = bf16rte(v);
    float hf = __uint_as_float((uint)h << 16);
    ushort l = bf16rte(v - hf);
    ahi[idx] = h;
    alo[idx] = l;
}

// ---------------- qkv weight split into 16x16x32 A-fragment order, hi/lo planes
__global__ __launch_bounds__(256) void k_aswz(const float* __restrict__ qkvw,
                                              ushort* __restrict__ aqh, ushort* __restrict__ aql) {
    int idx = blockIdx.x * 256 + threadIdx.x;     // 196608 total
    if (idx >= 196608) return;
    int j    = idx & 7;
    int lane = (idx >> 3) & 63;
    int t2   = idx >> 9;          // 0..383 = (h*3+p)*8+kk
    int kk   = t2 & 7;
    int hp   = t2 >> 3;
    int p    = hp % 3, h = hp / 3;
    int co = p * 256 + h * 16 + (lane & 15);
    int ci = kk * 32 + ((lane >> 4) << 3) + j;
    float v = qkvw[(size_t)co * 256 + ci];
    ushort hi = bf16rte(v);
    float hf = __uint_as_float((uint)hi << 16);
    aqh[idx] = hi;
    aql[idx] = bf16rte(v - hf);
}

// ---------------- pw weight -> 32x32 A-fragment order hi/lo bf16; also biasf = l1b+l2b
__global__ __launch_bounds__(256) void k_pswz(const float* __restrict__ pww,
                                              const float* __restrict__ l1b, const float* __restrict__ l2b,
                                              ushort* __restrict__ apwh, ushort* __restrict__ apwl,
                                              float* __restrict__ biasf) {
    int idx = blockIdx.x * 256 + threadIdx.x;     // 65536 total
    if (idx < 256) biasf[idx] = l1b[idx] + l2b[idx];
    if (idx >= 65536) return;
    int j    = idx & 7;
    int lane = (idx >> 3) & 63;
    int t2   = idx >> 9;          // 0..127 = cob*16+ks
    int ks   = t2 & 15;
    int cob  = t2 >> 4;
    int co = cob * 32 + (lane & 31);
    int ci = ks * 16 + ((lane >> 5) << 3) + j;
    float v = pww[(size_t)co * 256 + ci];
    ushort h = bf16rte(v);
    float hf = __uint_as_float((uint)h << 16);
    apwh[idx] = h;
    apwl[idx] = bf16rte(v - hf);
}

// ---------------- x -> pixel-major bf16 hi/lo planes: xT[b][pix][256ci]
__global__ __launch_bounds__(256) void k_cvt(const float* __restrict__ x,
                                             ushort* __restrict__ xhi, ushort* __restrict__ xlo) {
    __shared__ uint pk[32 * 265];
    int t = threadIdx.x;
    int bid = blockIdx.x;               // 4 * 512
    int b = bid >> 9;
    int px0 = (bid & 511) * 32;
    const float* xb = x + (size_t)b * CCH * HWSZ;
    for (int step = 0; step < 32; ++step) {
        int ci = step * 8 + (t >> 5);
        float v = xb[(size_t)ci * HWSZ + px0 + (t & 31)];
        ushort h = bf16rte(v);
        float hf = __uint_as_float((uint)h << 16);
        ushort l = bf16rte(v - hf);
        pk[(t & 31) * 265 + ci] = ((uint)h << 16) | l;
    }
    __syncthreads();
    int pxl = t >> 3, o = t & 7;
    uint* hp = (uint*)xhi;
    uint* lp = (uint*)xlo;
    size_t pb2 = ((size_t)b * HWSZ + px0 + pxl) * 128;
#pragma unroll
    for (int m = 0; m < 16; ++m) {
        int cip = m * 16 + o * 2;
        uint p0 = pk[pxl * 265 + cip];
        uint p1 = pk[pxl * 265 + cip + 1];
        hp[pb2 + m * 8 + o] = (p1 & 0xFFFF0000u) | (p0 >> 16);
        lp[pb2 + m * 8 + o] = (p1 << 16) | (p0 & 0xFFFFu);
    }
}

// ---------------- conv3x3 as implicit GEMM via mfma_f32_32x32x16_bf16 (3-term split)
// r5/r10-proven tiling; v5: __launch_bounds__(256,4) forces <=128 regs/wave
// (64 VGPR + 64 AGPR) -> 4 waves/SIMD to cover A-fragment L2 latency
__global__ __launch_bounds__(256, 4) void k_conv3m(const ushort* __restrict__ xhi, const ushort* __restrict__ xlo,
                                                   const ushort* __restrict__ afr_hi, const ushort* __restrict__ afr_lo,
                                                   const float* __restrict__ biasf, float* __restrict__ outp) {
    __shared__ __align__(16) ushort Xsh[12960];   // hi at byte 0, lo at byte 12960
    char* xsb = (char*)Xsh;

    int t = threadIdx.x;
    int bid = blockIdx.x;
    int cb = bid & 1;
    int t2 = bid >> 1;
    int tile_c = t2 & 7;
    int tile_r = (t2 >> 3) & 15;
    int b = t2 >> 7;
    int x0 = tile_c * 16, y0 = tile_r * 8;

    int w = t >> 6, lane = t & 63;
    int co_w = cb * 128 + (w >> 1) * 64;
    int pr0 = (w & 1) * 4;
    int pr_l = (lane & 31) >> 4;
    int pc = lane & 15;
    int kl = lane >> 5;
    int lb0 = (pr0 + 0 + pr_l) * 1296 + pc * 72 + kl * 16;
    int lb1 = (pr0 + 2 + pr_l) * 1296 + pc * 72 + kl * 16;

    const short8v* Ahi = (const short8v*)afr_hi;
    const short8v* Alo = (const short8v*)afr_lo;
    int cobase = (co_w >> 5) * 144 * 64;

    f32x16 c00 = {}, c01 = {}, c10 = {}, c11 = {};

    for (int cc = 0; cc < 8; ++cc) {
        __syncthreads();
#pragma unroll
        for (int it = 0; it < 6; ++it) {
            int i = t + it * 256;
            if (i < 1440) {
                int oct = i & 3;
                int j2 = i >> 2;
                int plane = j2 & 1;
                int loc = j2 >> 1;
                int r = loc / 18, c = loc - r * 18;
                int gy = y0 - 1 + r, gx = x0 - 1 + c;
                uint4 v = make_uint4(0u, 0u, 0u, 0u);
                if (gy >= 0 && gy < 128 && gx >= 0 && gx < 128) {
                    const ushort* src = plane ? xlo : xhi;
                    v = *(const uint4*)(src + ((size_t)(b * HWSZ + gy * 128 + gx) * 256 + cc * 32 + oct * 8));
                }
                *(uint4*)(xsb + plane * 12960 + loc * 72 + oct * 16) = v;
            }
        }
        __syncthreads();

        int baseA = cobase + cc * 18 * 64 + lane;
#pragma unroll
        for (int tap = 0; tap < 9; ++tap) {
            const int ky = tap / 3, kx = tap - ky * 3;
#pragma unroll
            for (int ks = 0; ks < 2; ++ks) {
                const int boff = ky * 1296 + kx * 72 + ks * 32;
                short8v b0h = *(const short8v*)(xsb + lb0 + boff);
                short8v b0l = *(const short8v*)(xsb + lb0 + boff + 12960);
                short8v b1h = *(const short8v*)(xsb + lb1 + boff);
                short8v b1l = *(const short8v*)(xsb + lb1 + boff + 12960);
                int ai = baseA + (tap * 2 + ks) * 64;
                short8v a0h = Ahi[ai];
                short8v a0l = Alo[ai];
                short8v a1h = Ahi[ai + 144 * 64];
                short8v a1l = Alo[ai + 144 * 64];
                c00 = __builtin_amdgcn_mfma_f32_32x32x16_bf16(a0h, b0h, c00, 0, 0, 0);
                c00 = __builtin_amdgcn_mfma_f32_32x32x16_bf16(a0h, b0l, c00, 0, 0, 0);
                c00 = __builtin_amdgcn_mfma_f32_32x32x16_bf16(a0l, b0h, c00, 0, 0, 0);
                c01 = __builtin_amdgcn_mfma_f32_32x32x16_bf16(a0h, b1h, c01, 0, 0, 0);
                c01 = __builtin_amdgcn_mfma_f32_32x32x16_bf16(a0h, b1l, c01, 0, 0, 0);
                c01 = __builtin_amdgcn_mfma_f32_32x32x16_bf16(a0l, b1h, c01, 0, 0, 0);
                c10 = __builtin_amdgcn_mfma_f32_32x32x16_bf16(a1h, b0h, c10, 0, 0, 0);
                c10 = __builtin_amdgcn_mfma_f32_32x32x16_bf16(a1h, b0l, c10, 0, 0, 0);
                c10 = __builtin_amdgcn_mfma_f32_32x32x16_bf16(a1l, b0h, c10, 0, 0, 0);
                c11 = __builtin_amdgcn_mfma_f32_32x32x16_bf16(a1h, b1h, c11, 0, 0, 0);
                c11 = __builtin_amdgcn_mfma_f32_32x32x16_bf16(a1h, b1l, c11, 0, 0, 0);
                c11 = __builtin_amdgcn_mfma_f32_32x32x16_bf16(a1l, b1h, c11, 0, 0, 0);
            }
        }
    }

    int colg = x0 + pc;
    int row0 = y0 + pr0 + pr_l;
    int row1 = row0 + 2;
#pragma unroll
    for (int r = 0; r < 16; ++r) {
        int rr = (r & 3) + 8 * (r >> 2) + 4 * kl;
        {
            int co = co_w + rr;
            float bv = biasf[co];
            float* ob = outp + ((size_t)(b * CCH + co)) * HWSZ;
            ob[row0 * 128 + colg] = c00[r] + bv;
            ob[row1 * 128 + colg] = c01[r] + bv;
        }
        {
            int co = co_w + 32 + rr;
            float bv = biasf[co];
            float* ob = outp + ((size_t)(b * CCH + co)) * HWSZ;
            ob[row0 * 128 + colg] = c10[r] + bv;
            ob[row1 * 128 + colg] = c11[r] + bv;
        }
    }
}

// ---------------- fused qkv(bf16 3-term MFMA) + window attention (r10 proven, 16 heads)
__global__ __launch_bounds__(256, 3) void k_attn(const ushort* __restrict__ xhi, const ushort* __restrict__ xlo,
                                                 const ushort* __restrict__ aqh, const ushort* __restrict__ aql,
                                                 const float* __restrict__ bt, float* __restrict__ attnout) {
    __shared__ float qkvb[2][48 * 64];   // 24576 B
    __shared__ float btl[16 * 225];      // 14400 B

    int t = threadIdx.x;
    int wv = __builtin_amdgcn_readfirstlane(t >> 6);
    int lane = t & 63;
    int widx = blockIdx.x;
    int b = widx >> 8;
    int rem = widx & 255;
    int hy = rem >> 4, wx = rem & 15;
    int y0 = hy * 8, x0 = wx * 8;

    for (int i = t; i < 3600; i += 256) {
        int rpi = i >> 4, hh = i & 15;
        btl[hh * 225 + rpi] = bt[i];
    }

    int tokb = (wv << 4) | (lane & 15);
    int pixb = (y0 + (tokb >> 3)) * 128 + (x0 + (tokb & 7));
    const ushort* xbh = xhi + ((size_t)b * HWSZ + pixb) * 256 + ((lane >> 4) << 3);
    const ushort* xbl = xlo + ((size_t)b * HWSZ + pixb) * 256 + ((lane >> 4) << 3);
    short8v bh_[8], bl_[8];
#pragma unroll
    for (int kk = 0; kk < 8; ++kk) {
        bh_[kk] = *(const short8v*)(xbh + kk * 32);
        bl_[kk] = *(const short8v*)(xbl + kk * 32);
    }

    const short8v* AhB = (const short8v*)aqh + lane;
    const short8v* AlB = (const short8v*)aql + lane;
    int wrow = ((lane >> 4) << 2);
    int wtok = (wv << 4) + (lane & 15);

    {
#pragma unroll
        for (int p = 0; p < 3; ++p) {
            f32x4 c = {};
#pragma unroll
            for (int kk = 0; kk < 8; ++kk) {
                short8v ah = AhB[(p * 8 + kk) * 64];
                short8v al = AlB[(p * 8 + kk) * 64];
                c = __builtin_amdgcn_mfma_f32_16x16x32_bf16(ah, bh_[kk], c, 0, 0, 0);
                c = __builtin_amdgcn_mfma_f32_16x16x32_bf16(ah, bl_[kk], c, 0, 0, 0);
                c = __builtin_amdgcn_mfma_f32_16x16x32_bf16(al, bh_[kk], c, 0, 0, 0);
            }
            float* bw = &qkvb[0][(p * 16 + wrow) * 64 + wtok];
            bw[0] = c[0]; bw[64] = c[1]; bw[128] = c[2]; bw[192] = c[3];
        }
    }
    __syncthreads();

    int irow = wv * 16 + (lane & 15);
    int jg = lane >> 4;
    int iy = irow >> 3, ix = irow & 7;

#pragma unroll 2
    for (int h = 0; h < 16; ++h) {
        int h2 = (h + 1) & 15;
        int nb = (h + 1) & 1;
        const short8v* Ah = AhB + (size_t)h2 * 24 * 64;
        const short8v* Al = AlB + (size_t)h2 * 24 * 64;
#pragma unroll
        for (int p = 0; p < 3; ++p) {
            f32x4 c = {};
#pragma unroll
            for (int kk = 0; kk < 8; ++kk) {
                short8v ah = Ah[(p * 8 + kk) * 64];
                short8v al = Al[(p * 8 + kk) * 64];
                c = __builtin_amdgcn_mfma_f32_16x16x32_bf16(ah, bh_[kk], c, 0, 0, 0);
                c = __builtin_amdgcn_mfma_f32_16x16x32_bf16(ah, bl_[kk], c, 0, 0, 0);
                c = __builtin_amdgcn_mfma_f32_16x16x32_bf16(al, bh_[kk], c, 0, 0, 0);
            }
            float* bw = &qkvb[nb][(p * 16 + wrow) * 64 + wtok];
            bw[0] = c[0]; bw[64] = c[1]; bw[128] = c[2]; bw[192] = c[3];
        }

        const float* buf = qkvb[h & 1];
        float qd[16];
#pragma unroll
        for (int d = 0; d < 16; ++d) qd[d] = buf[d * 64 + irow];
        float s[16];
#pragma unroll
        for (int jj = 0; jj < 16; ++jj) s[jj] = 0.f;
#pragma unroll
        for (int d = 0; d < 16; ++d) {
            const float* kp = &buf[(16 + d) * 64 + jg * 16];
#pragma unroll
            for (int m = 0; m < 4; ++m) {
                float4 kv = *(const float4*)(kp + m * 4);
                s[m * 4 + 0] += qd[d] * kv.x;
                s[m * 4 + 1] += qd[d] * kv.y;
                s[m * 4 + 2] += qd[d] * kv.z;
                s[m * 4 + 3] += qd[d] * kv.w;
            }
        }
#pragma unroll
        for (int jj = 0; jj < 16; ++jj) {
            int j = jg * 16 + jj;
            int jy = j >> 3, jx = j & 7;
            int rpi = (iy - jy + 7) * 15 + (ix - jx + 7);
            s[jj] = s[jj] * 0.25f + btl[h * 225 + rpi];
        }
        float mx = s[0];
#pragma unroll
        for (int jj = 1; jj < 16; ++jj) mx = fmaxf(mx, s[jj]);
        mx = fmaxf(mx, __shfl_xor(mx, 16));
        mx = fmaxf(mx, __shfl_xor(mx, 32));
        float ls = 0.f;
#pragma unroll
        for (int jj = 0; jj < 16; ++jj) { s[jj] = __expf(s[jj] - mx); ls += s[jj]; }
        ls += __shfl_xor(ls, 16);
        ls += __shfl_xor(ls, 32);
        float inv = 1.0f / ls;
#pragma unroll
        for (int d = 0; d < 16; ++d) {
            const float* vp = &buf[(32 + d) * 64 + jg * 16];
            float o0 = 0.f, o1 = 0.f;
#pragma unroll
            for (int m = 0; m < 4; ++m) {
                float4 vvv = *(const float4*)(vp + m * 4);
                o0 += s[m * 4 + 0] * vvv.x + s[m * 4 + 1] * vvv.y;
                o1 += s[m * 4 + 2] * vvv.z + s[m * 4 + 3] * vvv.w;
            }
            float o = o0 + o1;
            o += __shfl_xor(o, 16);
            o += __shfl_xor(o, 32);
            if (jg == 0)
                attnout[((size_t)(b * CCH + h * 16 + d)) * HWSZ + (y0 + iy) * 128 + (x0 + ix)] = o * inv;
        }
        __syncthreads();
    }
}

// ---------------- dual avg-pool + add local (r10 proven: 1 output/thread, max TLP)
__global__ __launch_bounds__(256) void k_pools(const float* __restrict__ attnout, const float* __restrict__ localb,
                                               float* __restrict__ sbuf) {
    for (int i = blockIdx.x * 256 + threadIdx.x; i < 4 * CCH * HWSZ; i += gridDim.x * 256) {
        int xc = i & 127;
        int y  = (i >> 7) & 127;
        int bc = i >> 14;
        const float* pl = attnout + (size_t)bc * HWSZ;
        float axs = 0.f;
#pragma unroll
        for (int d = -3; d <= 4; ++d) {
            int t2 = y + d;
            if (t2 >= 0 && t2 < 128) axs += pl[t2 * 128 + xc];
        }
        if (y >= 124) axs += pl[126 * 128 + xc];
        float ays = 0.f;
#pragma unroll
        for (int d = -3; d <= 4; ++d) {
            int t2 = xc + d;
            if (t2 >= 0 && t2 < 128) ays += pl[y * 128 + t2];
        }
        if (xc >= 124) ays += pl[y * 128 + 126];
        sbuf[i] = (axs + ays) * 0.125f + localb[i];
    }
}

// ---------------- depthwise 8x8 (reflect +1 pad, zero pad 3) + bn (r14 v2)
__device__ __forceinline__ void dw_loadrow(const float* __restrict__ sp, int trow, int j, float* dst) {
    if (trow < 0 || trow > 128) {
#pragma unroll
        for (int q = 0; q < 8; ++q) dst[q] = 0.f;
        return;
    }
    int sr = (trow == 128) ? 126 : trow;
    const float* rp = sp + sr * 128;
#pragma unroll
    for (int q = 0; q < 8; ++q) {
        int col = j - 3 + q;
        float v = 0.f;
        if (col >= 0 && col <= 128) v = rp[(col == 128) ? 126 : col];
        dst[q] = v;
    }
}

__global__ __launch_bounds__(256) void k_dw(const float* __restrict__ sbuf, const float* __restrict__ dww,
                                            const float* __restrict__ pscale, const float* __restrict__ pbias,
                                            float* __restrict__ tbuf) {
    int t = threadIdx.x;
    int j = t & 127;
    int yhalf = __builtin_amdgcn_readfirstlane(t >> 7);
    int ybase = yhalf * 64;
    int bid = blockIdx.x;          // 1024: c = bid&255, b = bid>>8
    int c = bid & 255;
    int b = bid >> 8;
    const float* sp = sbuf + ((size_t)(b * CCH + c)) * HWSZ;
    float wloc[64];
    const float* dwp = dww + c * 64;
#pragma unroll
    for (int i = 0; i < 64; ++i) wloc[i] = dwp[i];
    float scale = pscale[c], bias = pbias[c];

    float rbuf[8][8];
#pragma unroll
    for (int tr = -3; tr <= 4; ++tr) {
        dw_loadrow(sp, ybase + tr, j, rbuf[(tr + 8) & 7]);
    }
    float* op = tbuf + ((size_t)(b * CCH + c)) * HWSZ;
    for (int yb = 0; yb < 8; ++yb) {
#pragma unroll
        for (int k = 0; k < 8; ++k) {
            int y = ybase + yb * 8 + k;
            float a0 = 0.f, a1 = 0.f, a2 = 0.f, a3 = 0.f;
#pragma unroll
            for (int p = 0; p < 8; ++p) {
                const int slot = (k + 5 + p) & 7;
                float part = 0.f;
#pragma unroll
                for (int q = 0; q < 8; ++q) part += wloc[p * 8 + q] * rbuf[slot][q];
                if ((p & 3) == 0) a0 += part;
                else if ((p & 3) == 1) a1 += part;
                else if ((p & 3) == 2) a2 += part;
                else a3 += part;
            }
            op[y * 128 + j] = scale * ((a0 + a1) + (a2 + a3)) + bias;
            dw_loadrow(sp, y + 5, j, rbuf[(k + 5) & 7]);
        }
    }
}

// ---------------- pointwise 1x1 conv as bf16 3-term MFMA GEMM: 256co x 32px per block
__global__ __launch_bounds__(256) void k_pwm(const float* __restrict__ tbuf,
                                             const ushort* __restrict__ apwh, const ushort* __restrict__ apwl,
                                             float* __restrict__ outp) {
    __shared__ __align__(16) ushort pBh[32][264];   // [px][256 ci + 8 pad]
    __shared__ __align__(16) ushort pBl[32][264];

    int t = threadIdx.x;
    int bid = blockIdx.x;                // 2048: b = bid>>9, pxb = bid&511
    int b = bid >> 9;
    int px0 = (bid & 511) * 32;
    int px = t & 31;

    for (int it = 0; it < 32; ++it) {
        int ci = it * 8 + (t >> 5);
        float v = tbuf[((size_t)(b * CCH + ci)) * HWSZ + px0 + px];
        ushort h = bf16rte(v);
        float hf = __uint_as_float((uint)h << 16);
        pBh[px][ci] = h;
        pBl[px][ci] = bf16rte(v - hf);
    }
    __syncthreads();

    int w = t >> 6, lane = t & 63;
    int kl = lane >> 5;
    int pc = lane & 31;
    const short8v* Ah = (const short8v*)apwh;
    const short8v* Al = (const short8v*)apwl;
    int a0base = ((w * 2) * 16) * 64 + lane;       // cob0 = 2w
    int a1base = ((w * 2 + 1) * 16) * 64 + lane;   // cob1 = 2w+1

    f32x16 c0 = {}, c1 = {};
#pragma unroll
    for (int ks = 0; ks < 16; ++ks) {
        short8v bh = *(const short8v*)&pBh[pc][ks * 16 + kl * 8];
        short8v bl = *(const short8v*)&pBl[pc][ks * 16 + kl * 8];
        short8v a0h = Ah[a0base + ks * 64];
        short8v a0l = Al[a0base + ks * 64];
        short8v a1h = Ah[a1base + ks * 64];
        short8v a1l = Al[a1base + ks * 64];
        c0 = __builtin_amdgcn_mfma_f32_32x32x16_bf16(a0h, bh, c0, 0, 0, 0);
        c0 = __builtin_amdgcn_mfma_f32_32x32x16_bf16(a0h, bl, c0, 0, 0, 0);
        c0 = __builtin_amdgcn_mfma_f32_32x32x16_bf16(a0l, bh, c0, 0, 0, 0);
        c1 = __builtin_amdgcn_mfma_f32_32x32x16_bf16(a1h, bh, c1, 0, 0, 0);
        c1 = __builtin_amdgcn_mfma_f32_32x32x16_bf16(a1h, bl, c1, 0, 0, 0);
        c1 = __builtin_amdgcn_mfma_f32_32x32x16_bf16(a1l, bh, c1, 0, 0, 0);
    }

#pragma unroll
    for (int r = 0; r < 16; ++r) {
        int rr = (r & 3) + 8 * (r >> 2) + 4 * kl;
        {
            int co = w * 64 + rr;
            outp[((size_t)(b * CCH + co)) * HWSZ + px0 + pc] = c0[r];
        }
        {
            int co = w * 64 + 32 + rr;
            outp[((size_t)(b * CCH + co)) * HWSZ + px0 + pc] = c1[r];
        }
    }
}

extern "C" void kernel_launch(void* const* d_in, const int* in_sizes, int n_in,
                              void* d_out, int out_size, void* d_ws, size_t ws_size,
                              hipStream_t stream) {
    const float* x    = (const float*)d_in[0];
    const float* qkvw = (const float*)d_in[1];
    const float* l1w  = (const float*)d_in[2];
    const float* l1s  = (const float*)d_in[3];
    const float* l1b  = (const float*)d_in[4];
    const float* l2w  = (const float*)d_in[5];
    const float* l2s  = (const float*)d_in[6];
    const float* l2b  = (const float*)d_in[7];
    const float* dww  = (const float*)d_in[8];
    const float* ps   = (const float*)d_in[9];
    const float* pb   = (const float*)d_in[10];
    const float* pww  = (const float*)d_in[11];
    const float* bt   = (const float*)d_in[12];
    float* out = (float*)d_out;
    float* wsf = (float*)d_ws;

    const size_t nWf = 589824;          // kept for layout compatibility
    const size_t nPlane = 16777216;     // 4*256*128*128
    const size_t nAq = 196608;          // 16*3*8*64*8
    const size_t nApw = 65536;          // 8*16*64*8
    size_t need = (nWf + 256 + 3 * nPlane) * sizeof(float)
                + (2 * 589824 + 2 * nAq + 2 * nApw) * sizeof(ushort);
    if (ws_size < need) return;

    float* biasf   = wsf + nWf;
    float* attnout = wsf + nWf + 256;
    float* localb  = attnout + nPlane;
    float* sbuf    = localb + nPlane;
    float* tbuf    = attnout;                 // attnout dead after k_pools
    ushort* xhi = (ushort*)sbuf;              // aliases sbuf (dead until k_pools)
    ushort* xlo = xhi + nPlane;
    ushort* ahi = (ushort*)(sbuf + nPlane);   // after sbuf region
    ushort* alo = ahi + 589824;
    ushort* aqh = alo + 589824;
    ushort* aql = aqh + nAq;
    ushort* apwh = aql + nAq;
    ushort* apwl = apwh + nApw;

    k_wsplit<<<2304, 256, 0, stream>>>(l1w, l1s, l2w, l2s, ahi, alo);
    k_aswz  <<<768,  256, 0, stream>>>(qkvw, aqh, aql);
    k_pswz  <<<256,  256, 0, stream>>>(pww, l1b, l2b, apwh, apwl, biasf);
    k_cvt   <<<2048, 256, 0, stream>>>(x, xhi, xlo);
    k_conv3m<<<1024, 256, 0, stream>>>(xhi, xlo, ahi, alo, biasf, localb);
    k_attn  <<<1024, 256, 0, stream>>>(xhi, xlo, aqh, aql, bt, attnout);
    k_pools <<<4096, 256, 0, stream>>>(attnout, localb, sbuf);
    k_dw    <<<1024, 256, 0, stream>>>(sbuf, dww, ps, pb, tbuf);
    k_pwm   <<<2048, 256, 0, stream>>>(tbuf, apwh, apwl, out);
}

// Round 18
// 788.943 us; speedup vs baseline: 2.8747x; 2.8747x over previous
//
#include <hip/hip_runtime.h>
#include <cstddef>

#define HH 128
#define WW2 128
#define HWSZ (HH*WW2)
#define CCH 256

typedef __attribute__((ext_vector_type(8))) short short8v;   // 8 bf16 = 4 VGPR
typedef __attribute__((ext_vector_type(16))) float f32x16;   // MFMA 32x32 acc
typedef __attribute__((ext_vector_type(4)))  float f32x4;    // MFMA 16x16 acc

__device__ __forceinline__ ushort bf16rte(float v) {
    uint u = __float_as_uint(v);
    uint r = u + 0x7FFFu + ((u >> 16) & 1u);
    return (ushort)(r >> 16);
}

// ---------------- conv weight: fold (l1s*l1w + center l2s*l2w) AND split into
// 32x32 A-fragment order hi/lo bf16, in one pass (no Wf round-trip)
__global__ __launch_bounds__(256) void k_wsplit(const float* __restrict__ l1w, const float* __restrict__ l1s,
                                                const float* __restrict__ l2w, const float* __restrict__ l2s,
                                                ushort* __restrict__ ahi, ushort* __restrict__ alo) {
    int idx = blockIdx.x * 256 + threadIdx.x;     // 589824 total
    if (idx >= 589824) return;
    int j    = idx & 7;
    int lane = (idx >> 3) & 63;
    int t2   = idx >> 9;
    int kb   = t2 % 144;
    int cob  = t2 / 144;
    int cc  = kb / 18; int rem = kb - cc * 18; int tap = rem >> 1; int ks = rem & 1;
    int ci  = cc * 32 + ks * 16 + ((lane >> 5) << 3) + j;
    int co  = cob * 32 + (lane & 31);
    float v = l1s[co] * l1w[(size_t)co * 2304 + ci * 9 + tap];
    if (tap == 4) v += l2s[co] * l2w[(size_t)co * 256 + ci];
    ushort h = bf16rte(v);
    float hf = __uint_as_float((uint)h << 16);
    ushort l = bf16rte(v - hf);
    ahi[idx] = h;
    alo[idx] = l;
}

// ---------------- qkv weight split into 16x16x32 A-fragment order, hi/lo planes
__global__ __launch_bounds__(256) void k_aswz(const float* __restrict__ qkvw,
                                              ushort* __restrict__ aqh, ushort* __restrict__ aql) {
    int idx = blockIdx.x * 256 + threadIdx.x;     // 196608 total
    if (idx >= 196608) return;
    int j    = idx & 7;
    int lane = (idx >> 3) & 63;
    int t2   = idx >> 9;          // 0..383 = (h*3+p)*8+kk
    int kk   = t2 & 7;
    int hp   = t2 >> 3;
    int p    = hp % 3, h = hp / 3;
    int co = p * 256 + h * 16 + (lane & 15);
    int ci = kk * 32 + ((lane >> 4) << 3) + j;
    float v = qkvw[(size_t)co * 256 + ci];
    ushort hi = bf16rte(v);
    float hf = __uint_as_float((uint)hi << 16);
    aqh[idx] = hi;
    aql[idx] = bf16rte(v - hf);
}

// ---------------- pw weight -> 32x32 A-fragment order hi/lo bf16; also biasf = l1b+l2b
__global__ __launch_bounds__(256) void k_pswz(const float* __restrict__ pww,
                                              const float* __restrict__ l1b, const float* __restrict__ l2b,
                                              ushort* __restrict__ apwh, ushort* __restrict__ apwl,
                                              float* __restrict__ biasf) {
    int idx = blockIdx.x * 256 + threadIdx.x;     // 65536 total
    if (idx < 256) biasf[idx] = l1b[idx] + l2b[idx];
    if (idx >= 65536) return;
    int j    = idx & 7;
    int lane = (idx >> 3) & 63;
    int t2   = idx >> 9;          // 0..127 = cob*16+ks
    int ks   = t2 & 15;
    int cob  = t2 >> 4;
    int co = cob * 32 + (lane & 31);
    int ci = ks * 16 + ((lane >> 5) << 3) + j;
    float v = pww[(size_t)co * 256 + ci];
    ushort h = bf16rte(v);
    float hf = __uint_as_float((uint)h << 16);
    apwh[idx] = h;
    apwl[idx] = bf16rte(v - hf);
}

// ---------------- x -> pixel-major bf16 hi/lo planes: xT[b][pix][256ci]
__global__ __launch_bounds__(256) void k_cvt(const float* __restrict__ x,
                                             ushort* __restrict__ xhi, ushort* __restrict__ xlo) {
    __shared__ uint pk[32 * 265];
    int t = threadIdx.x;
    int bid = blockIdx.x;               // 4 * 512
    int b = bid >> 9;
    int px0 = (bid & 511) * 32;
    const float* xb = x + (size_t)b * CCH * HWSZ;
    for (int step = 0; step < 32; ++step) {
        int ci = step * 8 + (t >> 5);
        float v = xb[(size_t)ci * HWSZ + px0 + (t & 31)];
        ushort h = bf16rte(v);
        float hf = __uint_as_float((uint)h << 16);
        ushort l = bf16rte(v - hf);
        pk[(t & 31) * 265 + ci] = ((uint)h << 16) | l;
    }
    __syncthreads();
    int pxl = t >> 3, o = t & 7;
    uint* hp = (uint*)xhi;
    uint* lp = (uint*)xlo;
    size_t pb2 = ((size_t)b * HWSZ + px0 + pxl) * 128;
#pragma unroll
    for (int m = 0; m < 16; ++m) {
        int cip = m * 16 + o * 2;
        uint p0 = pk[pxl * 265 + cip];
        uint p1 = pk[pxl * 265 + cip + 1];
        hp[pb2 + m * 8 + o] = (p1 & 0xFFFF0000u) | (p0 >> 16);
        lp[pb2 + m * 8 + o] = (p1 << 16) | (p0 & 0xFFFFu);
    }
}

// ---------------- conv3x3 as implicit GEMM via mfma_f32_32x32x16_bf16 (3-term split)
// r5/r10-proven tiling: block = 128co x 128px; wave = 64co x 64px, 4 accs.
// NOTE: register budget (64 AGPR + ~96 VGPR) is intrinsic; forcing 4 waves/EU spills (r17).
__global__ __launch_bounds__(256) void k_conv3m(const ushort* __restrict__ xhi, const ushort* __restrict__ xlo,
                                                const ushort* __restrict__ afr_hi, const ushort* __restrict__ afr_lo,
                                                const float* __restrict__ biasf, float* __restrict__ outp) {
    __shared__ __align__(16) ushort Xsh[12960];   // hi at byte 0, lo at byte 12960
    char* xsb = (char*)Xsh;

    int t = threadIdx.x;
    int bid = blockIdx.x;
    int cb = bid & 1;
    int t2 = bid >> 1;
    int tile_c = t2 & 7;
    int tile_r = (t2 >> 3) & 15;
    int b = t2 >> 7;
    int x0 = tile_c * 16, y0 = tile_r * 8;

    int w = t >> 6, lane = t & 63;
    int co_w = cb * 128 + (w >> 1) * 64;
    int pr0 = (w & 1) * 4;
    int pr_l = (lane & 31) >> 4;
    int pc = lane & 15;
    int kl = lane >> 5;
    int lb0 = (pr0 + 0 + pr_l) * 1296 + pc * 72 + kl * 16;
    int lb1 = (pr0 + 2 + pr_l) * 1296 + pc * 72 + kl * 16;

    const short8v* Ahi = (const short8v*)afr_hi;
    const short8v* Alo = (const short8v*)afr_lo;
    int cobase = (co_w >> 5) * 144 * 64;

    f32x16 c00 = {}, c01 = {}, c10 = {}, c11 = {};

    for (int cc = 0; cc < 8; ++cc) {
        __syncthreads();
#pragma unroll
        for (int it = 0; it < 6; ++it) {
            int i = t + it * 256;
            if (i < 1440) {
                int oct = i & 3;
                int j2 = i >> 2;
                int plane = j2 & 1;
                int loc = j2 >> 1;
                int r = loc / 18, c = loc - r * 18;
                int gy = y0 - 1 + r, gx = x0 - 1 + c;
                uint4 v = make_uint4(0u, 0u, 0u, 0u);
                if (gy >= 0 && gy < 128 && gx >= 0 && gx < 128) {
                    const ushort* src = plane ? xlo : xhi;
                    v = *(const uint4*)(src + ((size_t)(b * HWSZ + gy * 128 + gx) * 256 + cc * 32 + oct * 8));
                }
                *(uint4*)(xsb + plane * 12960 + loc * 72 + oct * 16) = v;
            }
        }
        __syncthreads();

        int baseA = cobase + cc * 18 * 64 + lane;
#pragma unroll
        for (int tap = 0; tap < 9; ++tap) {
            const int ky = tap / 3, kx = tap - ky * 3;
#pragma unroll
            for (int ks = 0; ks < 2; ++ks) {
                const int boff = ky * 1296 + kx * 72 + ks * 32;
                short8v b0h = *(const short8v*)(xsb + lb0 + boff);
                short8v b0l = *(const short8v*)(xsb + lb0 + boff + 12960);
                short8v b1h = *(const short8v*)(xsb + lb1 + boff);
                short8v b1l = *(const short8v*)(xsb + lb1 + boff + 12960);
                int ai = baseA + (tap * 2 + ks) * 64;
                short8v a0h = Ahi[ai];
                short8v a0l = Alo[ai];
                short8v a1h = Ahi[ai + 144 * 64];
                short8v a1l = Alo[ai + 144 * 64];
                c00 = __builtin_amdgcn_mfma_f32_32x32x16_bf16(a0h, b0h, c00, 0, 0, 0);
                c00 = __builtin_amdgcn_mfma_f32_32x32x16_bf16(a0h, b0l, c00, 0, 0, 0);
                c00 = __builtin_amdgcn_mfma_f32_32x32x16_bf16(a0l, b0h, c00, 0, 0, 0);
                c01 = __builtin_amdgcn_mfma_f32_32x32x16_bf16(a0h, b1h, c01, 0, 0, 0);
                c01 = __builtin_amdgcn_mfma_f32_32x32x16_bf16(a0h, b1l, c01, 0, 0, 0);
                c01 = __builtin_amdgcn_mfma_f32_32x32x16_bf16(a0l, b1h, c01, 0, 0, 0);
                c10 = __builtin_amdgcn_mfma_f32_32x32x16_bf16(a1h, b0h, c10, 0, 0, 0);
                c10 = __builtin_amdgcn_mfma_f32_32x32x16_bf16(a1h, b0l, c10, 0, 0, 0);
                c10 = __builtin_amdgcn_mfma_f32_32x32x16_bf16(a1l, b0h, c10, 0, 0, 0);
                c11 = __builtin_amdgcn_mfma_f32_32x32x16_bf16(a1h, b1h, c11, 0, 0, 0);
                c11 = __builtin_amdgcn_mfma_f32_32x32x16_bf16(a1h, b1l, c11, 0, 0, 0);
                c11 = __builtin_amdgcn_mfma_f32_32x32x16_bf16(a1l, b1h, c11, 0, 0, 0);
            }
        }
    }

    int colg = x0 + pc;
    int row0 = y0 + pr0 + pr_l;
    int row1 = row0 + 2;
#pragma unroll
    for (int r = 0; r < 16; ++r) {
        int rr = (r & 3) + 8 * (r >> 2) + 4 * kl;
        {
            int co = co_w + rr;
            float bv = biasf[co];
            float* ob = outp + ((size_t)(b * CCH + co)) * HWSZ;
            ob[row0 * 128 + colg] = c00[r] + bv;
            ob[row1 * 128 + colg] = c01[r] + bv;
        }
        {
            int co = co_w + 32 + rr;
            float bv = biasf[co];
            float* ob = outp + ((size_t)(b * CCH + co)) * HWSZ;
            ob[row0 * 128 + colg] = c10[r] + bv;
            ob[row1 * 128 + colg] = c11[r] + bv;
        }
    }
}

// ---------------- fused qkv(bf16 3-term MFMA) + window attention (r10 proven, 16 heads)
__global__ __launch_bounds__(256, 3) void k_attn(const ushort* __restrict__ xhi, const ushort* __restrict__ xlo,
                                                 const ushort* __restrict__ aqh, const ushort* __restrict__ aql,
                                                 const float* __restrict__ bt, float* __restrict__ attnout) {
    __shared__ float qkvb[2][48 * 64];   // 24576 B
    __shared__ float btl[16 * 225];      // 14400 B

    int t = threadIdx.x;
    int wv = __builtin_amdgcn_readfirstlane(t >> 6);
    int lane = t & 63;
    int widx = blockIdx.x;
    int b = widx >> 8;
    int rem = widx & 255;
    int hy = rem >> 4, wx = rem & 15;
    int y0 = hy * 8, x0 = wx * 8;

    for (int i = t; i < 3600; i += 256) {
        int rpi = i >> 4, hh = i & 15;
        btl[hh * 225 + rpi] = bt[i];
    }

    int tokb = (wv << 4) | (lane & 15);
    int pixb = (y0 + (tokb >> 3)) * 128 + (x0 + (tokb & 7));
    const ushort* xbh = xhi + ((size_t)b * HWSZ + pixb) * 256 + ((lane >> 4) << 3);
    const ushort* xbl = xlo + ((size_t)b * HWSZ + pixb) * 256 + ((lane >> 4) << 3);
    short8v bh_[8], bl_[8];
#pragma unroll
    for (int kk = 0; kk < 8; ++kk) {
        bh_[kk] = *(const short8v*)(xbh + kk * 32);
        bl_[kk] = *(const short8v*)(xbl + kk * 32);
    }

    const short8v* AhB = (const short8v*)aqh + lane;
    const short8v* AlB = (const short8v*)aql + lane;
    int wrow = ((lane >> 4) << 2);
    int wtok = (wv << 4) + (lane & 15);

    {
#pragma unroll
        for (int p = 0; p < 3; ++p) {
            f32x4 c = {};
#pragma unroll
            for (int kk = 0; kk < 8; ++kk) {
                short8v ah = AhB[(p * 8 + kk) * 64];
                short8v al = AlB[(p * 8 + kk) * 64];
                c = __builtin_amdgcn_mfma_f32_16x16x32_bf16(ah, bh_[kk], c, 0, 0, 0);
                c = __builtin_amdgcn_mfma_f32_16x16x32_bf16(ah, bl_[kk], c, 0, 0, 0);
                c = __builtin_amdgcn_mfma_f32_16x16x32_bf16(al, bh_[kk], c, 0, 0, 0);
            }
            float* bw = &qkvb[0][(p * 16 + wrow) * 64 + wtok];
            bw[0] = c[0]; bw[64] = c[1]; bw[128] = c[2]; bw[192] = c[3];
        }
    }
    __syncthreads();

    int irow = wv * 16 + (lane & 15);
    int jg = lane >> 4;
    int iy = irow >> 3, ix = irow & 7;

#pragma unroll 2
    for (int h = 0; h < 16; ++h) {
        int h2 = (h + 1) & 15;
        int nb = (h + 1) & 1;
        const short8v* Ah = AhB + (size_t)h2 * 24 * 64;
        const short8v* Al = AlB + (size_t)h2 * 24 * 64;
#pragma unroll
        for (int p = 0; p < 3; ++p) {
            f32x4 c = {};
#pragma unroll
            for (int kk = 0; kk < 8; ++kk) {
                short8v ah = Ah[(p * 8 + kk) * 64];
                short8v al = Al[(p * 8 + kk) * 64];
                c = __builtin_amdgcn_mfma_f32_16x16x32_bf16(ah, bh_[kk], c, 0, 0, 0);
                c = __builtin_amdgcn_mfma_f32_16x16x32_bf16(ah, bl_[kk], c, 0, 0, 0);
                c = __builtin_amdgcn_mfma_f32_16x16x32_bf16(al, bh_[kk], c, 0, 0, 0);
            }
            float* bw = &qkvb[nb][(p * 16 + wrow) * 64 + wtok];
            bw[0] = c[0]; bw[64] = c[1]; bw[128] = c[2]; bw[192] = c[3];
        }

        const float* buf = qkvb[h & 1];
        float qd[16];
#pragma unroll
        for (int d = 0; d < 16; ++d) qd[d] = buf[d * 64 + irow];
        float s[16];
#pragma unroll
        for (int jj = 0; jj < 16; ++jj) s[jj] = 0.f;
#pragma unroll
        for (int d = 0; d < 16; ++d) {
            const float* kp = &buf[(16 + d) * 64 + jg * 16];
#pragma unroll
            for (int m = 0; m < 4; ++m) {
                float4 kv = *(const float4*)(kp + m * 4);
                s[m * 4 + 0] += qd[d] * kv.x;
                s[m * 4 + 1] += qd[d] * kv.y;
                s[m * 4 + 2] += qd[d] * kv.z;
                s[m * 4 + 3] += qd[d] * kv.w;
            }
        }
#pragma unroll
        for (int jj = 0; jj < 16; ++jj) {
            int j = jg * 16 + jj;
            int jy = j >> 3, jx = j & 7;
            int rpi = (iy - jy + 7) * 15 + (ix - jx + 7);
            s[jj] = s[jj] * 0.25f + btl[h * 225 + rpi];
        }
        float mx = s[0];
#pragma unroll
        for (int jj = 1; jj < 16; ++jj) mx = fmaxf(mx, s[jj]);
        mx = fmaxf(mx, __shfl_xor(mx, 16));
        mx = fmaxf(mx, __shfl_xor(mx, 32));
        float ls = 0.f;
#pragma unroll
        for (int jj = 0; jj < 16; ++jj) { s[jj] = __expf(s[jj] - mx); ls += s[jj]; }
        ls += __shfl_xor(ls, 16);
        ls += __shfl_xor(ls, 32);
        float inv = 1.0f / ls;
#pragma unroll
        for (int d = 0; d < 16; ++d) {
            const float* vp = &buf[(32 + d) * 64 + jg * 16];
            float o0 = 0.f, o1 = 0.f;
#pragma unroll
            for (int m = 0; m < 4; ++m) {
                float4 vvv = *(const float4*)(vp + m * 4);
                o0 += s[m * 4 + 0] * vvv.x + s[m * 4 + 1] * vvv.y;
                o1 += s[m * 4 + 2] * vvv.z + s[m * 4 + 3] * vvv.w;
            }
            float o = o0 + o1;
            o += __shfl_xor(o, 16);
            o += __shfl_xor(o, 32);
            if (jg == 0)
                attnout[((size_t)(b * CCH + h * 16 + d)) * HWSZ + (y0 + iy) * 128 + (x0 + ix)] = o * inv;
        }
        __syncthreads();
    }
}

// ---------------- dual avg-pool + add local (r10 proven: 1 output/thread, max TLP)
__global__ __launch_bounds__(256) void k_pools(const float* __restrict__ attnout, const float* __restrict__ localb,
                                               float* __restrict__ sbuf) {
    for (int i = blockIdx.x * 256 + threadIdx.x; i < 4 * CCH * HWSZ; i += gridDim.x * 256) {
        int xc = i & 127;
        int y  = (i >> 7) & 127;
        int bc = i >> 14;
        const float* pl = attnout + (size_t)bc * HWSZ;
        float axs = 0.f;
#pragma unroll
        for (int d = -3; d <= 4; ++d) {
            int t2 = y + d;
            if (t2 >= 0 && t2 < 128) axs += pl[t2 * 128 + xc];
        }
        if (y >= 124) axs += pl[126 * 128 + xc];
        float ays = 0.f;
#pragma unroll
        for (int d = -3; d <= 4; ++d) {
            int t2 = xc + d;
            if (t2 >= 0 && t2 < 128) ays += pl[y * 128 + t2];
        }
        if (xc >= 124) ays += pl[y * 128 + 126];
        sbuf[i] = (axs + ays) * 0.125f + localb[i];
    }
}

// ---------------- depthwise 8x8 (reflect +1 pad, zero pad 3) + bn (r14 v2)
__device__ __forceinline__ void dw_loadrow(const float* __restrict__ sp, int trow, int j, float* dst) {
    if (trow < 0 || trow > 128) {
#pragma unroll
        for (int q = 0; q < 8; ++q) dst[q] = 0.f;
        return;
    }
    int sr = (trow == 128) ? 126 : trow;
    const float* rp = sp + sr * 128;
#pragma unroll
    for (int q = 0; q < 8; ++q) {
        int col = j - 3 + q;
        float v = 0.f;
        if (col >= 0 && col <= 128) v = rp[(col == 128) ? 126 : col];
        dst[q] = v;
    }
}

__global__ __launch_bounds__(256) void k_dw(const float* __restrict__ sbuf, const float* __restrict__ dww,
                                            const float* __restrict__ pscale, const float* __restrict__ pbias,
                                            float* __restrict__ tbuf) {
    int t = threadIdx.x;
    int j = t & 127;
    int yhalf = __builtin_amdgcn_readfirstlane(t >> 7);
    int ybase = yhalf * 64;
    int bid = blockIdx.x;          // 1024: c = bid&255, b = bid>>8
    int c = bid & 255;
    int b = bid >> 8;
    const float* sp = sbuf + ((size_t)(b * CCH + c)) * HWSZ;
    float wloc[64];
    const float* dwp = dww + c * 64;
#pragma unroll
    for (int i = 0; i < 64; ++i) wloc[i] = dwp[i];
    float scale = pscale[c], bias = pbias[c];

    float rbuf[8][8];
#pragma unroll
    for (int tr = -3; tr <= 4; ++tr) {
        dw_loadrow(sp, ybase + tr, j, rbuf[(tr + 8) & 7]);
    }
    float* op = tbuf + ((size_t)(b * CCH + c)) * HWSZ;
    for (int yb = 0; yb < 8; ++yb) {
#pragma unroll
        for (int k = 0; k < 8; ++k) {
            int y = ybase + yb * 8 + k;
            float a0 = 0.f, a1 = 0.f, a2 = 0.f, a3 = 0.f;
#pragma unroll
            for (int p = 0; p < 8; ++p) {
                const int slot = (k + 5 + p) & 7;
                float part = 0.f;
#pragma unroll
                for (int q = 0; q < 8; ++q) part += wloc[p * 8 + q] * rbuf[slot][q];
                if ((p & 3) == 0) a0 += part;
                else if ((p & 3) == 1) a1 += part;
                else if ((p & 3) == 2) a2 += part;
                else a3 += part;
            }
            op[y * 128 + j] = scale * ((a0 + a1) + (a2 + a3)) + bias;
            dw_loadrow(sp, y + 5, j, rbuf[(k + 5) & 7]);
        }
    }
}

// ---------------- pointwise 1x1 conv as bf16 3-term MFMA GEMM: 256co x 32px per block
__global__ __launch_bounds__(256) void k_pwm(const float* __restrict__ tbuf,
                                             const ushort* __restrict__ apwh, const ushort* __restrict__ apwl,
                                             float* __restrict__ outp) {
    __shared__ __align__(16) ushort pBh[32][264];   // [px][256 ci + 8 pad]
    __shared__ __align__(16) ushort pBl[32][264];

    int t = threadIdx.x;
    int bid = blockIdx.x;                // 2048: b = bid>>9, pxb = bid&511
    int b = bid >> 9;
    int px0 = (bid & 511) * 32;
    int px = t & 31;

    for (int it = 0; it < 32; ++it) {
        int ci = it * 8 + (t >> 5);
        float v = tbuf[((size_t)(b * CCH + ci)) * HWSZ + px0 + px];
        ushort h = bf16rte(v);
        float hf = __uint_as_float((uint)h << 16);
        pBh[px][ci] = h;
        pBl[px][ci] = bf16rte(v - hf);
    }
    __syncthreads();

    int w = t >> 6, lane = t & 63;
    int kl = lane >> 5;
    int pc = lane & 31;
    const short8v* Ah = (const short8v*)apwh;
    const short8v* Al = (const short8v*)apwl;
    int a0base = ((w * 2) * 16) * 64 + lane;       // cob0 = 2w
    int a1base = ((w * 2 + 1) * 16) * 64 + lane;   // cob1 = 2w+1

    f32x16 c0 = {}, c1 = {};
#pragma unroll
    for (int ks = 0; ks < 16; ++ks) {
        short8v bh = *(const short8v*)&pBh[pc][ks * 16 + kl * 8];
        short8v bl = *(const short8v*)&pBl[pc][ks * 16 + kl * 8];
        short8v a0h = Ah[a0base + ks * 64];
        short8v a0l = Al[a0base + ks * 64];
        short8v a1h = Ah[a1base + ks * 64];
        short8v a1l = Al[a1base + ks * 64];
        c0 = __builtin_amdgcn_mfma_f32_32x32x16_bf16(a0h, bh, c0, 0, 0, 0);
        c0 = __builtin_amdgcn_mfma_f32_32x32x16_bf16(a0h, bl, c0, 0, 0, 0);
        c0 = __builtin_amdgcn_mfma_f32_32x32x16_bf16(a0l, bh, c0, 0, 0, 0);
        c1 = __builtin_amdgcn_mfma_f32_32x32x16_bf16(a1h, bh, c1, 0, 0, 0);
        c1 = __builtin_amdgcn_mfma_f32_32x32x16_bf16(a1h, bl, c1, 0, 0, 0);
        c1 = __builtin_amdgcn_mfma_f32_32x32x16_bf16(a1l, bh, c1, 0, 0, 0);
    }

#pragma unroll
    for (int r = 0; r < 16; ++r) {
        int rr = (r & 3) + 8 * (r >> 2) + 4 * kl;
        {
            int co = w * 64 + rr;
            outp[((size_t)(b * CCH + co)) * HWSZ + px0 + pc] = c0[r];
        }
        {
            int co = w * 64 + 32 + rr;
            outp[((size_t)(b * CCH + co)) * HWSZ + px0 + pc] = c1[r];
        }
    }
}

extern "C" void kernel_launch(void* const* d_in, const int* in_sizes, int n_in,
                              void* d_out, int out_size, void* d_ws, size_t ws_size,
                              hipStream_t stream) {
    const float* x    = (const float*)d_in[0];
    const float* qkvw = (const float*)d_in[1];
    const float* l1w  = (const float*)d_in[2];
    const float* l1s  = (const float*)d_in[3];
    const float* l1b  = (const float*)d_in[4];
    const float* l2w  = (const float*)d_in[5];
    const float* l2s  = (const float*)d_in[6];
    const float* l2b  = (const float*)d_in[7];
    const float* dww  = (const float*)d_in[8];
    const float* ps   = (const float*)d_in[9];
    const float* pb   = (const float*)d_in[10];
    const float* pww  = (const float*)d_in[11];
    const float* bt   = (const float*)d_in[12];
    float* out = (float*)d_out;
    float* wsf = (float*)d_ws;

    const size_t nWf = 589824;          // kept for layout compatibility
    const size_t nPlane = 16777216;     // 4*256*128*128
    const size_t nAq = 196608;          // 16*3*8*64*8
    const size_t nApw = 65536;          // 8*16*64*8
    size_t need = (nWf + 256 + 3 * nPlane) * sizeof(float)
                + (2 * 589824 + 2 * nAq + 2 * nApw) * sizeof(ushort);
    if (ws_size < need) return;

    float* biasf   = wsf + nWf;
    float* attnout = wsf + nWf + 256;
    float* localb  = attnout + nPlane;
    float* sbuf    = localb + nPlane;
    float* tbuf    = attnout;                 // attnout dead after k_pools
    ushort* xhi = (ushort*)sbuf;              // aliases sbuf (dead until k_pools)
    ushort* xlo = xhi + nPlane;
    ushort* ahi = (ushort*)(sbuf + nPlane);   // after sbuf region
    ushort* alo = ahi + 589824;
    ushort* aqh = alo + 589824;
    ushort* aql = aqh + nAq;
    ushort* apwh = aql + nAq;
    ushort* apwl = apwh + nApw;

    k_wsplit<<<2304, 256, 0, stream>>>(l1w, l1s, l2w, l2s, ahi, alo);
    k_aswz  <<<768,  256, 0, stream>>>(qkvw, aqh, aql);
    k_pswz  <<<256,  256, 0, stream>>>(pww, l1b, l2b, apwh, apwl, biasf);
    k_cvt   <<<2048, 256, 0, stream>>>(x, xhi, xlo);
    k_conv3m<<<1024, 256, 0, stream>>>(xhi, xlo, ahi, alo, biasf, localb);
    k_attn  <<<1024, 256, 0, stream>>>(xhi, xlo, aqh, aql, bt, attnout);
    k_pools <<<4096, 256, 0, stream>>>(attnout, localb, sbuf);
    k_dw    <<<1024, 256, 0, stream>>>(sbuf, dww, ps, pb, tbuf);
    k_pwm   <<<2048, 256, 0, stream>>>(tbuf, apwh, apwl, out);
}

// Round 19
// 771.272 us; speedup vs baseline: 2.9406x; 1.0229x over previous
//
#include <hip/hip_runtime.h>
#include <cstddef>

#define HH 128
#define WW2 128
#define HWSZ (HH*WW2)
#define CCH 256

typedef __attribute__((ext_vector_type(8))) short short8v;   // 8 bf16 = 4 VGPR
typedef __attribute__((ext_vector_type(16))) float f32x16;   // MFMA 32x32 acc
typedef __attribute__((ext_vector_type(4)))  float f32x4;    // MFMA 16x16 acc

__device__ __forceinline__ ushort bf16rte(float v) {
    uint u = __float_as_uint(v);
    uint r = u + 0x7FFFu + ((u >> 16) & 1u);
    return (ushort)(r >> 16);
}

// ---------------- conv weight: fold (l1s*l1w + center l2s*l2w) AND split into
// 32x32 A-fragment order hi/lo bf16, in one pass (no Wf round-trip)
__global__ __launch_bounds__(256) void k_wsplit(const float* __restrict__ l1w, const float* __restrict__ l1s,
                                                const float* __restrict__ l2w, const float* __restrict__ l2s,
                                                ushort* __restrict__ ahi, ushort* __restrict__ alo) {
    int idx = blockIdx.x * 256 + threadIdx.x;     // 589824 total
    if (idx >= 589824) return;
    int j    = idx & 7;
    int lane = (idx >> 3) & 63;
    int t2   = idx >> 9;
    int kb   = t2 % 144;
    int cob  = t2 / 144;
    int cc  = kb / 18; int rem = kb - cc * 18; int tap = rem >> 1; int ks = rem & 1;
    int ci  = cc * 32 + ks * 16 + ((lane >> 5) << 3) + j;
    int co  = cob * 32 + (lane & 31);
    float v = l1s[co] * l1w[(size_t)co * 2304 + ci * 9 + tap];
    if (tap == 4) v += l2s[co] * l2w[(size_t)co * 256 + ci];
    ushort h = bf16rte(v);
    float hf = __uint_as_float((uint)h << 16);
    ushort l = bf16rte(v - hf);
    ahi[idx] = h;
    alo[idx] = l;
}

// ---------------- qkv weight split into 16x16x32 A-fragment order, hi/lo planes
__global__ __launch_bounds__(256) void k_aswz(const float* __restrict__ qkvw,
                                              ushort* __restrict__ aqh, ushort* __restrict__ aql) {
    int idx = blockIdx.x * 256 + threadIdx.x;     // 196608 total
    if (idx >= 196608) return;
    int j    = idx & 7;
    int lane = (idx >> 3) & 63;
    int t2   = idx >> 9;          // 0..383 = (h*3+p)*8+kk
    int kk   = t2 & 7;
    int hp   = t2 >> 3;
    int p    = hp % 3, h = hp / 3;
    int co = p * 256 + h * 16 + (lane & 15);
    int ci = kk * 32 + ((lane >> 4) << 3) + j;
    float v = qkvw[(size_t)co * 256 + ci];
    ushort hi = bf16rte(v);
    float hf = __uint_as_float((uint)hi << 16);
    aqh[idx] = hi;
    aql[idx] = bf16rte(v - hf);
}

// ---------------- pw weight -> 32x32 A-fragment order hi/lo bf16; also biasf = l1b+l2b
__global__ __launch_bounds__(256) void k_pswz(const float* __restrict__ pww,
                                              const float* __restrict__ l1b, const float* __restrict__ l2b,
                                              ushort* __restrict__ apwh, ushort* __restrict__ apwl,
                                              float* __restrict__ biasf) {
    int idx = blockIdx.x * 256 + threadIdx.x;     // 65536 total
    if (idx < 256) biasf[idx] = l1b[idx] + l2b[idx];
    if (idx >= 65536) return;
    int j    = idx & 7;
    int lane = (idx >> 3) & 63;
    int t2   = idx >> 9;          // 0..127 = cob*16+ks
    int ks   = t2 & 15;
    int cob  = t2 >> 4;
    int co = cob * 32 + (lane & 31);
    int ci = ks * 16 + ((lane >> 5) << 3) + j;
    float v = pww[(size_t)co * 256 + ci];
    ushort h = bf16rte(v);
    float hf = __uint_as_float((uint)h << 16);
    apwh[idx] = h;
    apwl[idx] = bf16rte(v - hf);
}

// ---------------- x -> pixel-major bf16 hi/lo planes: xT[b][pix][256ci]
__global__ __launch_bounds__(256) void k_cvt(const float* __restrict__ x,
                                             ushort* __restrict__ xhi, ushort* __restrict__ xlo) {
    __shared__ uint pk[32 * 265];
    int t = threadIdx.x;
    int bid = blockIdx.x;               // 4 * 512
    int b = bid >> 9;
    int px0 = (bid & 511) * 32;
    const float* xb = x + (size_t)b * CCH * HWSZ;
    for (int step = 0; step < 32; ++step) {
        int ci = step * 8 + (t >> 5);
        float v = xb[(size_t)ci * HWSZ + px0 + (t & 31)];
        ushort h = bf16rte(v);
        float hf = __uint_as_float((uint)h << 16);
        ushort l = bf16rte(v - hf);
        pk[(t & 31) * 265 + ci] = ((uint)h << 16) | l;
    }
    __syncthreads();
    int pxl = t >> 3, o = t & 7;
    uint* hp = (uint*)xhi;
    uint* lp = (uint*)xlo;
    size_t pb2 = ((size_t)b * HWSZ + px0 + pxl) * 128;
#pragma unroll
    for (int m = 0; m < 16; ++m) {
        int cip = m * 16 + o * 2;
        uint p0 = pk[pxl * 265 + cip];
        uint p1 = pk[pxl * 265 + cip + 1];
        hp[pb2 + m * 8 + o] = (p1 & 0xFFFF0000u) | (p0 >> 16);
        lp[pb2 + m * 8 + o] = (p1 << 16) | (p0 & 0xFFFFu);
    }
}

// ---------------- conv3x3 as implicit GEMM via mfma_f32_32x32x16_bf16 (3-term split)
// r5/r10-proven tiling: block = 128co x 128px; wave = 64co x 64px, 4 accs.
// NOTE: register budget (64 AGPR + ~96 VGPR) is intrinsic; forcing 4 waves/EU spills (r17).
__global__ __launch_bounds__(256) void k_conv3m(const ushort* __restrict__ xhi, const ushort* __restrict__ xlo,
                                                const ushort* __restrict__ afr_hi, const ushort* __restrict__ afr_lo,
                                                const float* __restrict__ biasf, float* __restrict__ outp) {
    __shared__ __align__(16) ushort Xsh[12960];   // hi at byte 0, lo at byte 12960
    char* xsb = (char*)Xsh;

    int t = threadIdx.x;
    int bid = blockIdx.x;
    int cb = bid & 1;
    int t2 = bid >> 1;
    int tile_c = t2 & 7;
    int tile_r = (t2 >> 3) & 15;
    int b = t2 >> 7;
    int x0 = tile_c * 16, y0 = tile_r * 8;

    int w = t >> 6, lane = t & 63;
    int co_w = cb * 128 + (w >> 1) * 64;
    int pr0 = (w & 1) * 4;
    int pr_l = (lane & 31) >> 4;
    int pc = lane & 15;
    int kl = lane >> 5;
    int lb0 = (pr0 + 0 + pr_l) * 1296 + pc * 72 + kl * 16;
    int lb1 = (pr0 + 2 + pr_l) * 1296 + pc * 72 + kl * 16;

    const short8v* Ahi = (const short8v*)afr_hi;
    const short8v* Alo = (const short8v*)afr_lo;
    int cobase = (co_w >> 5) * 144 * 64;

    f32x16 c00 = {}, c01 = {}, c10 = {}, c11 = {};

    for (int cc = 0; cc < 8; ++cc) {
        __syncthreads();
#pragma unroll
        for (int it = 0; it < 6; ++it) {
            int i = t + it * 256;
            if (i < 1440) {
                int oct = i & 3;
                int j2 = i >> 2;
                int plane = j2 & 1;
                int loc = j2 >> 1;
                int r = loc / 18, c = loc - r * 18;
                int gy = y0 - 1 + r, gx = x0 - 1 + c;
                uint4 v = make_uint4(0u, 0u, 0u, 0u);
                if (gy >= 0 && gy < 128 && gx >= 0 && gx < 128) {
                    const ushort* src = plane ? xlo : xhi;
                    v = *(const uint4*)(src + ((size_t)(b * HWSZ + gy * 128 + gx) * 256 + cc * 32 + oct * 8));
                }
                *(uint4*)(xsb + plane * 12960 + loc * 72 + oct * 16) = v;
            }
        }
        __syncthreads();

        int baseA = cobase + cc * 18 * 64 + lane;
#pragma unroll
        for (int tap = 0; tap < 9; ++tap) {
            const int ky = tap / 3, kx = tap - ky * 3;
#pragma unroll
            for (int ks = 0; ks < 2; ++ks) {
                const int boff = ky * 1296 + kx * 72 + ks * 32;
                short8v b0h = *(const short8v*)(xsb + lb0 + boff);
                short8v b0l = *(const short8v*)(xsb + lb0 + boff + 12960);
                short8v b1h = *(const short8v*)(xsb + lb1 + boff);
                short8v b1l = *(const short8v*)(xsb + lb1 + boff + 12960);
                int ai = baseA + (tap * 2 + ks) * 64;
                short8v a0h = Ahi[ai];
                short8v a0l = Alo[ai];
                short8v a1h = Ahi[ai + 144 * 64];
                short8v a1l = Alo[ai + 144 * 64];
                c00 = __builtin_amdgcn_mfma_f32_32x32x16_bf16(a0h, b0h, c00, 0, 0, 0);
                c00 = __builtin_amdgcn_mfma_f32_32x32x16_bf16(a0h, b0l, c00, 0, 0, 0);
                c00 = __builtin_amdgcn_mfma_f32_32x32x16_bf16(a0l, b0h, c00, 0, 0, 0);
                c01 = __builtin_amdgcn_mfma_f32_32x32x16_bf16(a0h, b1h, c01, 0, 0, 0);
                c01 = __builtin_amdgcn_mfma_f32_32x32x16_bf16(a0h, b1l, c01, 0, 0, 0);
                c01 = __builtin_amdgcn_mfma_f32_32x32x16_bf16(a0l, b1h, c01, 0, 0, 0);
                c10 = __builtin_amdgcn_mfma_f32_32x32x16_bf16(a1h, b0h, c10, 0, 0, 0);
                c10 = __builtin_amdgcn_mfma_f32_32x32x16_bf16(a1h, b0l, c10, 0, 0, 0);
                c10 = __builtin_amdgcn_mfma_f32_32x32x16_bf16(a1l, b0h, c10, 0, 0, 0);
                c11 = __builtin_amdgcn_mfma_f32_32x32x16_bf16(a1h, b1h, c11, 0, 0, 0);
                c11 = __builtin_amdgcn_mfma_f32_32x32x16_bf16(a1h, b1l, c11, 0, 0, 0);
                c11 = __builtin_amdgcn_mfma_f32_32x32x16_bf16(a1l, b1h, c11, 0, 0, 0);
            }
        }
    }

    int colg = x0 + pc;
    int row0 = y0 + pr0 + pr_l;
    int row1 = row0 + 2;
#pragma unroll
    for (int r = 0; r < 16; ++r) {
        int rr = (r & 3) + 8 * (r >> 2) + 4 * kl;
        {
            int co = co_w + rr;
            float bv = biasf[co];
            float* ob = outp + ((size_t)(b * CCH + co)) * HWSZ;
            ob[row0 * 128 + colg] = c00[r] + bv;
            ob[row1 * 128 + colg] = c01[r] + bv;
        }
        {
            int co = co_w + 32 + rr;
            float bv = biasf[co];
            float* ob = outp + ((size_t)(b * CCH + co)) * HWSZ;
            ob[row0 * 128 + colg] = c10[r] + bv;
            ob[row1 * 128 + colg] = c11[r] + bv;
        }
    }
}

// ---------------- fused qkv(bf16 3-term MFMA) + window attention
// r18 proven structure + (a) s_setprio(1) around MFMA cluster (T5, m191-positive),
// (b) skip redundant 17th head compute at h=15 (wave-uniform branch)
__global__ __launch_bounds__(256, 3) void k_attn(const ushort* __restrict__ xhi, const ushort* __restrict__ xlo,
                                                 const ushort* __restrict__ aqh, const ushort* __restrict__ aql,
                                                 const float* __restrict__ bt, float* __restrict__ attnout) {
    __shared__ float qkvb[2][48 * 64];   // 24576 B
    __shared__ float btl[16 * 225];      // 14400 B

    int t = threadIdx.x;
    int wv = __builtin_amdgcn_readfirstlane(t >> 6);
    int lane = t & 63;
    int widx = blockIdx.x;
    int b = widx >> 8;
    int rem = widx & 255;
    int hy = rem >> 4, wx = rem & 15;
    int y0 = hy * 8, x0 = wx * 8;

    for (int i = t; i < 3600; i += 256) {
        int rpi = i >> 4, hh = i & 15;
        btl[hh * 225 + rpi] = bt[i];
    }

    int tokb = (wv << 4) | (lane & 15);
    int pixb = (y0 + (tokb >> 3)) * 128 + (x0 + (tokb & 7));
    const ushort* xbh = xhi + ((size_t)b * HWSZ + pixb) * 256 + ((lane >> 4) << 3);
    const ushort* xbl = xlo + ((size_t)b * HWSZ + pixb) * 256 + ((lane >> 4) << 3);
    short8v bh_[8], bl_[8];
#pragma unroll
    for (int kk = 0; kk < 8; ++kk) {
        bh_[kk] = *(const short8v*)(xbh + kk * 32);
        bl_[kk] = *(const short8v*)(xbl + kk * 32);
    }

    const short8v* AhB = (const short8v*)aqh + lane;
    const short8v* AlB = (const short8v*)aql + lane;
    int wrow = ((lane >> 4) << 2);
    int wtok = (wv << 4) + (lane & 15);

    {
        __builtin_amdgcn_s_setprio(1);
#pragma unroll
        for (int p = 0; p < 3; ++p) {
            f32x4 c = {};
#pragma unroll
            for (int kk = 0; kk < 8; ++kk) {
                short8v ah = AhB[(p * 8 + kk) * 64];
                short8v al = AlB[(p * 8 + kk) * 64];
                c = __builtin_amdgcn_mfma_f32_16x16x32_bf16(ah, bh_[kk], c, 0, 0, 0);
                c = __builtin_amdgcn_mfma_f32_16x16x32_bf16(ah, bl_[kk], c, 0, 0, 0);
                c = __builtin_amdgcn_mfma_f32_16x16x32_bf16(al, bh_[kk], c, 0, 0, 0);
            }
            float* bw = &qkvb[0][(p * 16 + wrow) * 64 + wtok];
            bw[0] = c[0]; bw[64] = c[1]; bw[128] = c[2]; bw[192] = c[3];
        }
        __builtin_amdgcn_s_setprio(0);
    }
    __syncthreads();

    int irow = wv * 16 + (lane & 15);
    int jg = lane >> 4;
    int iy = irow >> 3, ix = irow & 7;

#pragma unroll 2
    for (int h = 0; h < 16; ++h) {
        int h2 = (h + 1) & 15;
        int nb = (h + 1) & 1;
        if (h2 != 0) {   // wave-uniform: skip redundant recompute of head 0 at h=15
            const short8v* Ah = AhB + (size_t)h2 * 24 * 64;
            const short8v* Al = AlB + (size_t)h2 * 24 * 64;
            __builtin_amdgcn_s_setprio(1);
#pragma unroll
            for (int p = 0; p < 3; ++p) {
                f32x4 c = {};
#pragma unroll
                for (int kk = 0; kk < 8; ++kk) {
                    short8v ah = Ah[(p * 8 + kk) * 64];
                    short8v al = Al[(p * 8 + kk) * 64];
                    c = __builtin_amdgcn_mfma_f32_16x16x32_bf16(ah, bh_[kk], c, 0, 0, 0);
                    c = __builtin_amdgcn_mfma_f32_16x16x32_bf16(ah, bl_[kk], c, 0, 0, 0);
                    c = __builtin_amdgcn_mfma_f32_16x16x32_bf16(al, bh_[kk], c, 0, 0, 0);
                }
                float* bw = &qkvb[nb][(p * 16 + wrow) * 64 + wtok];
                bw[0] = c[0]; bw[64] = c[1]; bw[128] = c[2]; bw[192] = c[3];
            }
            __builtin_amdgcn_s_setprio(0);
        }

        const float* buf = qkvb[h & 1];
        float qd[16];
#pragma unroll
        for (int d = 0; d < 16; ++d) qd[d] = buf[d * 64 + irow];
        float s[16];
#pragma unroll
        for (int jj = 0; jj < 16; ++jj) s[jj] = 0.f;
#pragma unroll
        for (int d = 0; d < 16; ++d) {
            const float* kp = &buf[(16 + d) * 64 + jg * 16];
#pragma unroll
            for (int m = 0; m < 4; ++m) {
                float4 kv = *(const float4*)(kp + m * 4);
                s[m * 4 + 0] += qd[d] * kv.x;
                s[m * 4 + 1] += qd[d] * kv.y;
                s[m * 4 + 2] += qd[d] * kv.z;
                s[m * 4 + 3] += qd[d] * kv.w;
            }
        }
#pragma unroll
        for (int jj = 0; jj < 16; ++jj) {
            int j = jg * 16 + jj;
            int jy = j >> 3, jx = j & 7;
            int rpi = (iy - jy + 7) * 15 + (ix - jx + 7);
            s[jj] = s[jj] * 0.25f + btl[h * 225 + rpi];
        }
        float mx = s[0];
#pragma unroll
        for (int jj = 1; jj < 16; ++jj) mx = fmaxf(mx, s[jj]);
        mx = fmaxf(mx, __shfl_xor(mx, 16));
        mx = fmaxf(mx, __shfl_xor(mx, 32));
        float ls = 0.f;
#pragma unroll
        for (int jj = 0; jj < 16; ++jj) { s[jj] = __expf(s[jj] - mx); ls += s[jj]; }
        ls += __shfl_xor(ls, 16);
        ls += __shfl_xor(ls, 32);
        float inv = 1.0f / ls;
#pragma unroll
        for (int d = 0; d < 16; ++d) {
            const float* vp = &buf[(32 + d) * 64 + jg * 16];
            float o0 = 0.f, o1 = 0.f;
#pragma unroll
            for (int m = 0; m < 4; ++m) {
                float4 vvv = *(const float4*)(vp + m * 4);
                o0 += s[m * 4 + 0] * vvv.x + s[m * 4 + 1] * vvv.y;
                o1 += s[m * 4 + 2] * vvv.z + s[m * 4 + 3] * vvv.w;
            }
            float o = o0 + o1;
            o += __shfl_xor(o, 16);
            o += __shfl_xor(o, 32);
            if (jg == 0)
                attnout[((size_t)(b * CCH + h * 16 + d)) * HWSZ + (y0 + iy) * 128 + (x0 + ix)] = o * inv;
        }
        __syncthreads();
    }
}

// ---------------- dual avg-pool + add local (r10 proven: 1 output/thread, max TLP)
__global__ __launch_bounds__(256) void k_pools(const float* __restrict__ attnout, const float* __restrict__ localb,
                                               float* __restrict__ sbuf) {
    for (int i = blockIdx.x * 256 + threadIdx.x; i < 4 * CCH * HWSZ; i += gridDim.x * 256) {
        int xc = i & 127;
        int y  = (i >> 7) & 127;
        int bc = i >> 14;
        const float* pl = attnout + (size_t)bc * HWSZ;
        float axs = 0.f;
#pragma unroll
        for (int d = -3; d <= 4; ++d) {
            int t2 = y + d;
            if (t2 >= 0 && t2 < 128) axs += pl[t2 * 128 + xc];
        }
        if (y >= 124) axs += pl[126 * 128 + xc];
        float ays = 0.f;
#pragma unroll
        for (int d = -3; d <= 4; ++d) {
            int t2 = xc + d;
            if (t2 >= 0 && t2 < 128) ays += pl[y * 128 + t2];
        }
        if (xc >= 124) ays += pl[y * 128 + 126];
        sbuf[i] = (axs + ays) * 0.125f + localb[i];
    }
}

// ---------------- depthwise 8x8 (reflect +1 pad, zero pad 3) + bn (r14 v2)
__device__ __forceinline__ void dw_loadrow(const float* __restrict__ sp, int trow, int j, float* dst) {
    if (trow < 0 || trow > 128) {
#pragma unroll
        for (int q = 0; q < 8; ++q) dst[q] = 0.f;
        return;
    }
    int sr = (trow == 128) ? 126 : trow;
    const float* rp = sp + sr * 128;
#pragma unroll
    for (int q = 0; q < 8; ++q) {
        int col = j - 3 + q;
        float v = 0.f;
        if (col >= 0 && col <= 128) v = rp[(col == 128) ? 126 : col];
        dst[q] = v;
    }
}

__global__ __launch_bounds__(256) void k_dw(const float* __restrict__ sbuf, const float* __restrict__ dww,
                                            const float* __restrict__ pscale, const float* __restrict__ pbias,
                                            float* __restrict__ tbuf) {
    int t = threadIdx.x;
    int j = t & 127;
    int yhalf = __builtin_amdgcn_readfirstlane(t >> 7);
    int ybase = yhalf * 64;
    int bid = blockIdx.x;          // 1024: c = bid&255, b = bid>>8
    int c = bid & 255;
    int b = bid >> 8;
    const float* sp = sbuf + ((size_t)(b * CCH + c)) * HWSZ;
    float wloc[64];
    const float* dwp = dww + c * 64;
#pragma unroll
    for (int i = 0; i < 64; ++i) wloc[i] = dwp[i];
    float scale = pscale[c], bias = pbias[c];

    float rbuf[8][8];
#pragma unroll
    for (int tr = -3; tr <= 4; ++tr) {
        dw_loadrow(sp, ybase + tr, j, rbuf[(tr + 8) & 7]);
    }
    float* op = tbuf + ((size_t)(b * CCH + c)) * HWSZ;
    for (int yb = 0; yb < 8; ++yb) {
#pragma unroll
        for (int k = 0; k < 8; ++k) {
            int y = ybase + yb * 8 + k;
            float a0 = 0.f, a1 = 0.f, a2 = 0.f, a3 = 0.f;
#pragma unroll
            for (int p = 0; p < 8; ++p) {
                const int slot = (k + 5 + p) & 7;
                float part = 0.f;
#pragma unroll
                for (int q = 0; q < 8; ++q) part += wloc[p * 8 + q] * rbuf[slot][q];
                if ((p & 3) == 0) a0 += part;
                else if ((p & 3) == 1) a1 += part;
                else if ((p & 3) == 2) a2 += part;
                else a3 += part;
            }
            op[y * 128 + j] = scale * ((a0 + a1) + (a2 + a3)) + bias;
            dw_loadrow(sp, y + 5, j, rbuf[(k + 5) & 7]);
        }
    }
}

// ---------------- pointwise 1x1 conv as bf16 3-term MFMA GEMM: 256co x 32px per block
__global__ __launch_bounds__(256) void k_pwm(const float* __restrict__ tbuf,
                                             const ushort* __restrict__ apwh, const ushort* __restrict__ apwl,
                                             float* __restrict__ outp) {
    __shared__ __align__(16) ushort pBh[32][264];   // [px][256 ci + 8 pad]
    __shared__ __align__(16) ushort pBl[32][264];

    int t = threadIdx.x;
    int bid = blockIdx.x;                // 2048: b = bid>>9, pxb = bid&511
    int b = bid >> 9;
    int px0 = (bid & 511) * 32;
    int px = t & 31;

    for (int it = 0; it < 32; ++it) {
        int ci = it * 8 + (t >> 5);
        float v = tbuf[((size_t)(b * CCH + ci)) * HWSZ + px0 + px];
        ushort h = bf16rte(v);
        float hf = __uint_as_float((uint)h << 16);
        pBh[px][ci] = h;
        pBl[px][ci] = bf16rte(v - hf);
    }
    __syncthreads();

    int w = t >> 6, lane = t & 63;
    int kl = lane >> 5;
    int pc = lane & 31;
    const short8v* Ah = (const short8v*)apwh;
    const short8v* Al = (const short8v*)apwl;
    int a0base = ((w * 2) * 16) * 64 + lane;       // cob0 = 2w
    int a1base = ((w * 2 + 1) * 16) * 64 + lane;   // cob1 = 2w+1

    f32x16 c0 = {}, c1 = {};
#pragma unroll
    for (int ks = 0; ks < 16; ++ks) {
        short8v bh = *(const short8v*)&pBh[pc][ks * 16 + kl * 8];
        short8v bl = *(const short8v*)&pBl[pc][ks * 16 + kl * 8];
        short8v a0h = Ah[a0base + ks * 64];
        short8v a0l = Al[a0base + ks * 64];
        short8v a1h = Ah[a1base + ks * 64];
        short8v a1l = Al[a1base + ks * 64];
        c0 = __builtin_amdgcn_mfma_f32_32x32x16_bf16(a0h, bh, c0, 0, 0, 0);
        c0 = __builtin_amdgcn_mfma_f32_32x32x16_bf16(a0h, bl, c0, 0, 0, 0);
        c0 = __builtin_amdgcn_mfma_f32_32x32x16_bf16(a0l, bh, c0, 0, 0, 0);
        c1 = __builtin_amdgcn_mfma_f32_32x32x16_bf16(a1h, bh, c1, 0, 0, 0);
        c1 = __builtin_amdgcn_mfma_f32_32x32x16_bf16(a1h, bl, c1, 0, 0, 0);
        c1 = __builtin_amdgcn_mfma_f32_32x32x16_bf16(a1l, bh, c1, 0, 0, 0);
    }

#pragma unroll
    for (int r = 0; r < 16; ++r) {
        int rr = (r & 3) + 8 * (r >> 2) + 4 * kl;
        {
            int co = w * 64 + rr;
            outp[((size_t)(b * CCH + co)) * HWSZ + px0 + pc] = c0[r];
        }
        {
            int co = w * 64 + 32 + rr;
            outp[((size_t)(b * CCH + co)) * HWSZ + px0 + pc] = c1[r];
        }
    }
}

extern "C" void kernel_launch(void* const* d_in, const int* in_sizes, int n_in,
                              void* d_out, int out_size, void* d_ws, size_t ws_size,
                              hipStream_t stream) {
    const float* x    = (const float*)d_in[0];
    const float* qkvw = (const float*)d_in[1];
    const float* l1w  = (const float*)d_in[2];
    const float* l1s  = (const float*)d_in[3];
    const float* l1b  = (const float*)d_in[4];
    const float* l2w  = (const float*)d_in[5];
    const float* l2s  = (const float*)d_in[6];
    const float* l2b  = (const float*)d_in[7];
    const float* dww  = (const float*)d_in[8];
    const float* ps   = (const float*)d_in[9];
    const float* pb   = (const float*)d_in[10];
    const float* pww  = (const float*)d_in[11];
    const float* bt   = (const float*)d_in[12];
    float* out = (float*)d_out;
    float* wsf = (float*)d_ws;

    const size_t nWf = 589824;          // kept for layout compatibility
    const size_t nPlane = 16777216;     // 4*256*128*128
    const size_t nAq = 196608;          // 16*3*8*64*8
    const size_t nApw = 65536;          // 8*16*64*8
    size_t need = (nWf + 256 + 3 * nPlane) * sizeof(float)
                + (2 * 589824 + 2 * nAq + 2 * nApw) * sizeof(ushort);
    if (ws_size < need) return;

    float* biasf   = wsf + nWf;
    float* attnout = wsf + nWf + 256;
    float* localb  = attnout + nPlane;
    float* sbuf    = localb + nPlane;
    float* tbuf    = attnout;                 // attnout dead after k_pools
    ushort* xhi = (ushort*)sbuf;              // aliases sbuf (dead until k_pools)
    ushort* xlo = xhi + nPlane;
    ushort* ahi = (ushort*)(sbuf + nPlane);   // after sbuf region
    ushort* alo = ahi + 589824;
    ushort* aqh = alo + 589824;
    ushort* aql = aqh + nAq;
    ushort* apwh = aql + nAq;
    ushort* apwl = apwh + nApw;

    k_wsplit<<<2304, 256, 0, stream>>>(l1w, l1s, l2w, l2s, ahi, alo);
    k_aswz  <<<768,  256, 0, stream>>>(qkvw, aqh, aql);
    k_pswz  <<<256,  256, 0, stream>>>(pww, l1b, l2b, apwh, apwl, biasf);
    k_cvt   <<<2048, 256, 0, stream>>>(x, xhi, xlo);
    k_conv3m<<<1024, 256, 0, stream>>>(xhi, xlo, ahi, alo, biasf, localb);
    k_attn  <<<1024, 256, 0, stream>>>(xhi, xlo, aqh, aql, bt, attnout);
    k_pools <<<4096, 256, 0, stream>>>(attnout, localb, sbuf);
    k_dw    <<<1024, 256, 0, stream>>>(sbuf, dww, ps, pb, tbuf);
    k_pwm   <<<2048, 256, 0, stream>>>(tbuf, apwh, apwl, out);
}